// Round 2
// baseline (2688.725 us; speedup 1.0000x reference)
//
#include <hip/hip_runtime.h>
#include <stdint.h>

using short8  = __attribute__((ext_vector_type(8))) short;
using floatx4 = __attribute__((ext_vector_type(4))) float;

typedef unsigned short u16;
typedef unsigned int u32;
typedef unsigned long long u64;

__device__ __forceinline__ float bs2f(u16 u) { return __uint_as_float(((u32)u) << 16); }
__device__ __forceinline__ u16 f2bs(float f) {
  u32 x = __float_as_uint(f);
  x += 0x7FFFu + ((x >> 16) & 1u);   // RNE
  return (u16)(x >> 16);
}
__device__ __forceinline__ float lo16(u32 u) { return __uint_as_float(u << 16); }
__device__ __forceinline__ float hi16(u32 u) { return __uint_as_float(u & 0xFFFF0000u); }

// ---------------------------------------------------------------------------
// fp32 -> bf16 weight conversion (RNE)
// ---------------------------------------------------------------------------
__global__ __launch_bounds__(256) void cvt_k(const float* __restrict__ src,
                                             u16* __restrict__ dst, int n) {
  int i = blockIdx.x * 256 + threadIdx.x;
  if (i < n) dst[i] = f2bs(src[i]);
}

// ---------------------------------------------------------------------------
// LIF reservoir: 32 blocks (1/batch) x 512 threads (1/neuron), exact fp32.
// rec[r] = z @ Wres[:,r] maintained incrementally from per-wave change masks.
// ---------------------------------------------------------------------------
__device__ __forceinline__ float gather4(const float* __restrict__ Wcol, u64 m, int base) {
  float s0 = 0.f, s1 = 0.f, s2 = 0.f, s3 = 0.f;
  while (m) {
    int i0 = __builtin_ctzll(m); m &= m - 1;
    s0 += Wcol[(size_t)(base + i0) << 9];
    if (m) { int i1 = __builtin_ctzll(m); m &= m - 1; s1 += Wcol[(size_t)(base + i1) << 9]; }
    if (m) { int i2 = __builtin_ctzll(m); m &= m - 1; s2 += Wcol[(size_t)(base + i2) << 9]; }
    if (m) { int i3 = __builtin_ctzll(m); m &= m - 1; s3 += Wcol[(size_t)(base + i3) << 9]; }
  }
  return (s0 + s1) + (s2 + s3);
}

__global__ __launch_bounds__(512) void reservoir_k(
    const float* __restrict__ x,    // [32,1024,8] fp32
    const float* __restrict__ Win,  // [8,512]
    const float* __restrict__ Wres, // [512,512]
    u16* __restrict__ zout)         // [32,1024,512] bf16 (0.0/1.0, exact)
{
  const int b = blockIdx.x;
  const int r = threadIdx.x;
  const int wave = r >> 6, lane = r & 63;
  float win[8];
#pragma unroll
  for (int i = 0; i < 8; ++i) win[i] = Win[i * 512 + r];
  __shared__ u64 s_on[2][8];
  __shared__ u64 s_off[2][8];
  const float* Wcol = Wres + r;
  const float* xb = x + (size_t)b * 8192;
  u16* zb = zout + (size_t)b * 524288 + r;
  float v = 0.f, ic = 0.f, rec = 0.f;
  int zprev = 0;
  for (int t = 0; t < 1024; ++t) {
    const float4 xa = *(const float4*)(xb + (size_t)t * 8);
    const float4 xc = *(const float4*)(xb + (size_t)t * 8 + 4);
    // v_dec = v + 0.004*(-v + i)
    const float vdec = __fadd_rn(v, __fmul_rn(0.004f, __fadd_rn(-v, ic)));
    const float xm = __fadd_rn(vdec, -0.1f);
    const int zc = (xm > 0.f) ? 1 : 0;
    v = zc ? 0.f : vdec;
    const u64 bon = __ballot(zc && !zprev);
    const u64 boff = __ballot(!zc && zprev);
    if (lane == 0) { s_on[t & 1][wave] = bon; s_off[t & 1][wave] = boff; }
    float cur = 0.f;
    cur = fmaf(win[0], xa.x, cur);
    cur = fmaf(win[1], xa.y, cur);
    cur = fmaf(win[2], xa.z, cur);
    cur = fmaf(win[3], xa.w, cur);
    cur = fmaf(win[4], xc.x, cur);
    cur = fmaf(win[5], xc.y, cur);
    cur = fmaf(win[6], xc.z, cur);
    cur = fmaf(win[7], xc.w, cur);
    // i_new = i*0.8 + (cur + rec),  rec corresponds to z_{t-1}
    ic = __fadd_rn(__fmul_rn(ic, 0.8f), __fadd_rn(cur, rec));
    zb[(size_t)t * 512] = zc ? (u16)0x3F80 : (u16)0;
    __syncthreads();
#pragma unroll 1
    for (int w = 0; w < 8; ++w) {
      const u64 mon = s_on[t & 1][w];
      const u64 moff = s_off[t & 1][w];
      if (mon)  rec += gather4(Wcol, mon,  w << 6);
      if (moff) rec -= gather4(Wcol, moff, w << 6);
    }
    zprev = zc;
  }
}

// ---------------------------------------------------------------------------
// Generic bf16 MFMA GEMM: C = epilogue(A @ B^T * scale + bias)
// A [M,K] row-major (lda), B [N,K] row-major (ldb), both bf16. fp32 bias.
// BK=32, tile BM=WM*64, BN=WN*64, 4x4 16x16x32 frags/wave. LDS stride 40.
// ---------------------------------------------------------------------------
enum { MODE_BF16 = 0, MODE_F32 = 1, MODE_DUAL = 2, MODE_QKV = 3, MODE_AVC = 4 };

template <int WM, int WN, int MODE>
__global__ __launch_bounds__(WM * WN * 64) void gemm_bt(
    const u16* __restrict__ A, const u16* __restrict__ B,
    const float* __restrict__ bias, void* __restrict__ C0,
    void* __restrict__ C1, void* __restrict__ C2, int K, int lda, int ldb,
    int ldc, long long sA, long long sB, long long sC, int pair0, float scale,
    int relu)
{
  constexpr int BM = WM * 64, BN = WN * 64, BK = 32, LDK = 40;
  constexpr int NT = WM * WN * 64;
  __shared__ u16 As[BM * LDK];
  __shared__ u16 Bs[BN * LDK];
  const int tid = threadIdx.x;
  const int bz = blockIdx.z;
  const u16* Ab = A + (size_t)bz * sA + (size_t)blockIdx.y * BM * lda;
  const u16* Bb = B + (size_t)bz * sB + (size_t)blockIdx.x * BN * ldb;
  const int wavei = tid >> 6, lane = tid & 63;
  const int r16 = lane & 15, quad = lane >> 4;
  const int wm = (wavei % WM) * 64, wn = (wavei / WM) * 64;
  floatx4 acc[4][4] = {};
  for (int k0 = 0; k0 < K; k0 += BK) {
#pragma unroll
    for (int idx = tid; idx < BM * 4; idx += NT) {
      int row = idx >> 2, kc = (idx & 3) << 3;
      *(uint4*)&As[row * LDK + kc] = *(const uint4*)(Ab + (size_t)row * lda + k0 + kc);
    }
#pragma unroll
    for (int idx = tid; idx < BN * 4; idx += NT) {
      int row = idx >> 2, kc = (idx & 3) << 3;
      *(uint4*)&Bs[row * LDK + kc] = *(const uint4*)(Bb + (size_t)row * ldb + k0 + kc);
    }
    __syncthreads();
    short8 af[4], bfr[4];
#pragma unroll
    for (int i = 0; i < 4; ++i)
      af[i] = *(const short8*)&As[(wm + i * 16 + r16) * LDK + quad * 8];
#pragma unroll
    for (int i = 0; i < 4; ++i)
      bfr[i] = *(const short8*)&Bs[(wn + i * 16 + r16) * LDK + quad * 8];
#pragma unroll
    for (int i = 0; i < 4; ++i)
#pragma unroll
      for (int j = 0; j < 4; ++j)
        acc[i][j] = __builtin_amdgcn_mfma_f32_16x16x32_bf16(af[i], bfr[j], acc[i][j], 0, 0, 0);
    __syncthreads();
  }
#pragma unroll
  for (int i = 0; i < 4; ++i) {
#pragma unroll
    for (int j = 0; j < 4; ++j) {
#pragma unroll
      for (int q = 0; q < 4; ++q) {
        const int m = blockIdx.y * BM + wm + i * 16 + quad * 4 + q;
        const int n = blockIdx.x * BN + wn + j * 16 + r16;
        float val = acc[i][j][q] * scale;
        if (bias) val += bias[n];
        if (relu) val = fmaxf(val, 0.f);
        if constexpr (MODE == MODE_BF16) {
          ((u16*)C0)[(size_t)bz * sC + (size_t)m * ldc + n] = f2bs(val);
        } else if constexpr (MODE == MODE_F32) {
          ((float*)C0)[(size_t)m * ldc + n] = val;
        } else if constexpr (MODE == MODE_DUAL) {
          ((float*)C0)[(size_t)m * ldc + n] = val;
          ((u16*)C1)[(size_t)m * ldc + n] = f2bs(val);
        } else if constexpr (MODE == MODE_QKV) {
          const int b = m >> 10, s = m & 1023;
          const u16 outv = f2bs(val);
          const int h = (n & 255) >> 6, d = n & 63;
          if (n < 256)
            ((u16*)C0)[(((size_t)(b * 4 + h)) * 1024 + s) * 64 + d] = outv;  // q [B,H,S,dh]
          else if (n < 512)
            ((u16*)C1)[(((size_t)(b * 4 + h)) * 1024 + s) * 64 + d] = outv;  // k [B,H,S,dh]
          else
            ((u16*)C2)[(((size_t)(b * 4 + h)) * 64 + d) * 1024 + s] = outv;  // v^T [B,H,dh,S]
        } else if constexpr (MODE == MODE_AVC) {
          const int p = pair0 + bz;
          const size_t coff = (size_t)(p >> 2) * 262144 + (size_t)(p & 3) * 64;
          ((u16*)C0)[coff + (size_t)m * 256 + n] = f2bs(val);  // merged [B*S, H*dh]
        }
      }
    }
  }
}

// ---------------------------------------------------------------------------
// Row softmax over 1024 bf16, in place. One wave per row (16 elems/lane).
// ---------------------------------------------------------------------------
__global__ __launch_bounds__(256) void softmax_k(u16* __restrict__ s) {
  const int row = blockIdx.x * 4 + (threadIdx.x >> 6);
  const int lane = threadIdx.x & 63;
  u16* p = s + (size_t)row * 1024 + lane * 16;
  const uint4 u0 = *(const uint4*)p;
  const uint4 u1 = *(const uint4*)(p + 8);
  float f[16] = {lo16(u0.x), hi16(u0.x), lo16(u0.y), hi16(u0.y),
                 lo16(u0.z), hi16(u0.z), lo16(u0.w), hi16(u0.w),
                 lo16(u1.x), hi16(u1.x), lo16(u1.y), hi16(u1.y),
                 lo16(u1.z), hi16(u1.z), lo16(u1.w), hi16(u1.w)};
  float mx = f[0];
#pragma unroll
  for (int i = 1; i < 16; ++i) mx = fmaxf(mx, f[i]);
#pragma unroll
  for (int off = 32; off > 0; off >>= 1) mx = fmaxf(mx, __shfl_xor(mx, off));
  float sum = 0.f;
#pragma unroll
  for (int i = 0; i < 16; ++i) { f[i] = __expf(f[i] - mx); sum += f[i]; }
#pragma unroll
  for (int off = 32; off > 0; off >>= 1) sum += __shfl_xor(sum, off);
  const float inv = 1.f / sum;
  u32 o[8];
#pragma unroll
  for (int i = 0; i < 8; ++i)
    o[i] = (u32)f2bs(f[2 * i] * inv) | ((u32)f2bs(f[2 * i + 1] * inv) << 16);
  *(uint4*)p = make_uint4(o[0], o[1], o[2], o[3]);
  *(uint4*)(p + 8) = make_uint4(o[4], o[5], o[6], o[7]);
}

// ---------------------------------------------------------------------------
// Fused residual-add + LayerNorm over 256 fp32; writes fp32 and/or bf16.
// One wave per row (4 elems/lane).
// ---------------------------------------------------------------------------
__global__ __launch_bounds__(256) void ln_k(const float* __restrict__ x,
                                            const float* __restrict__ add,
                                            const float* __restrict__ g,
                                            const float* __restrict__ bta,
                                            float* __restrict__ y32,
                                            u16* __restrict__ y16) {
  const int row = blockIdx.x * 4 + (threadIdx.x >> 6);
  const int lane = threadIdx.x & 63;
  const size_t base = (size_t)row * 256 + lane * 4;
  const float4 xv = *(const float4*)(x + base);
  const float4 av = *(const float4*)(add + base);
  float sv[4] = {xv.x + av.x, xv.y + av.y, xv.z + av.z, xv.w + av.w};
  float sum = sv[0] + sv[1] + sv[2] + sv[3];
#pragma unroll
  for (int off = 32; off > 0; off >>= 1) sum += __shfl_xor(sum, off);
  const float mean = sum * (1.f / 256.f);
  float var = 0.f;
  float d[4];
#pragma unroll
  for (int i = 0; i < 4; ++i) { d[i] = sv[i] - mean; var += d[i] * d[i]; }
#pragma unroll
  for (int off = 32; off > 0; off >>= 1) var += __shfl_xor(var, off);
  var *= (1.f / 256.f);
  const float inv = 1.f / sqrtf(var + 1e-5f);
  float yv[4];
#pragma unroll
  for (int i = 0; i < 4; ++i)
    yv[i] = d[i] * inv * g[lane * 4 + i] + bta[lane * 4 + i];
  if (y32) *(float4*)(y32 + base) = make_float4(yv[0], yv[1], yv[2], yv[3]);
  if (y16) {
    const u32 p0 = (u32)f2bs(yv[0]) | ((u32)f2bs(yv[1]) << 16);
    const u32 p1 = (u32)f2bs(yv[2]) | ((u32)f2bs(yv[3]) << 16);
    *(uint2*)(y16 + base) = make_uint2(p0, p1);
  }
}

// ---------------------------------------------------------------------------
extern "C" void kernel_launch(void* const* d_in, const int* in_sizes, int n_in,
                              void* d_out, int out_size, void* d_ws,
                              size_t ws_size, hipStream_t stream) {
  (void)in_sizes; (void)n_in; (void)out_size; (void)ws_size;
  const float* x     = (const float*)d_in[0];   // [32,1024,8]
  const float* Win   = (const float*)d_in[1];   // [8,512]
  const float* Wres  = (const float*)d_in[2];   // [512,512]
  const float* Wread = (const float*)d_in[3];   // [256,512]
  const float* bread = (const float*)d_in[4];   // [256]
  const float* Wqkv  = (const float*)d_in[5];   // [2,768,256]
  const float* bqkv  = (const float*)d_in[6];   // [2,768]
  const float* Wo    = (const float*)d_in[7];   // [2,256,256]
  const float* bo    = (const float*)d_in[8];   // [2,256]
  const float* g1    = (const float*)d_in[9];
  const float* b1    = (const float*)d_in[10];
  const float* g2    = (const float*)d_in[11];
  const float* b2    = (const float*)d_in[12];
  const float* W1    = (const float*)d_in[13];  // [2,1024,256]
  const float* c1    = (const float*)d_in[14];  // [2,1024]
  const float* W2    = (const float*)d_in[15];  // [2,256,1024]
  const float* c2    = (const float*)d_in[16];  // [2,256]

  char* ws = (char*)d_ws;
  size_t off = 0;
  auto carve = [&](size_t bytes) {
    char* p = ws + off;
    off += (bytes + 255) & ~(size_t)255;
    return p;
  };
  u16* z      = (u16*)carve((size_t)32 * 1024 * 512 * 2);    // 33.6 MB spikes (bf16)
  u16* wrd16  = (u16*)carve((size_t)256 * 512 * 2);          // bf16 weights:
  u16* wqkv16 = (u16*)carve((size_t)2 * 768 * 256 * 2);
  u16* wo16   = (u16*)carve((size_t)2 * 256 * 256 * 2);
  u16* w116   = (u16*)carve((size_t)2 * 1024 * 256 * 2);
  u16* w216   = (u16*)carve((size_t)2 * 256 * 1024 * 2);
  u16* q_s    = (u16*)carve((size_t)128 * 1024 * 64 * 2);    // [B*H,S,dh]
  u16* k_s    = (u16*)carve((size_t)128 * 1024 * 64 * 2);
  u16* v_t    = (u16*)carve((size_t)128 * 64 * 1024 * 2);    // [B*H,dh,S]
  float* h32  = (float*)carve((size_t)32768 * 256 * 4);      // residual fp32
  float* lin  = (float*)carve((size_t)32768 * 256 * 4);      // o-proj/ff2 fp32
  u16* h16    = (u16*)carve((size_t)32768 * 256 * 2);        // bf16 GEMM input
  u16* ff1    = (u16*)carve((size_t)32768 * 1024 * 2);       // ff1 out (aliases scores)
  u16* o16    = h16;   // attention-out reuses h16 (qkv already consumed it)
  u16* scores = ff1;   // 32-pair score chunk == ff1 size (64 MB)

  // weight conversions (fp32 -> bf16)
  cvt_k<<<dim3(512), dim3(256), 0, stream>>>(Wread, wrd16, 131072);
  cvt_k<<<dim3(1536), dim3(256), 0, stream>>>(Wqkv, wqkv16, 393216);
  cvt_k<<<dim3(512), dim3(256), 0, stream>>>(Wo, wo16, 131072);
  cvt_k<<<dim3(2048), dim3(256), 0, stream>>>(W1, w116, 524288);
  cvt_k<<<dim3(2048), dim3(256), 0, stream>>>(W2, w216, 524288);

  reservoir_k<<<dim3(32), dim3(512), 0, stream>>>(x, Win, Wres, z);

  // readout: h = z @ Wread^T + bread  (dual fp32 + bf16)
  gemm_bt<2, 2, MODE_DUAL><<<dim3(2, 256, 1), dim3(256), 0, stream>>>(
      z, wrd16, bread, h32, h16, nullptr, 512, 512, 512, 256, 0, 0, 0, 0, 1.0f, 0);

  for (int l = 0; l < 2; ++l) {
    // qkv + scatter into q_s / k_s / v_t
    gemm_bt<2, 2, MODE_QKV><<<dim3(6, 256, 1), dim3(256), 0, stream>>>(
        h16, wqkv16 + (size_t)l * 196608, bqkv + l * 768, q_s, k_s, v_t, 256,
        256, 256, 0, 0, 0, 0, 0, 1.0f, 0);
    // attention in chunks of 32 (b,h)-pairs
    for (int ch = 0; ch < 128; ch += 32) {
      gemm_bt<2, 2, MODE_BF16><<<dim3(8, 8, 32), dim3(256), 0, stream>>>(
          q_s + (size_t)ch * 65536, k_s + (size_t)ch * 65536, nullptr, scores,
          nullptr, nullptr, 64, 64, 64, 1024, 65536, 65536, 1048576, 0,
          0.125f, 0);
      softmax_k<<<dim3(8192), dim3(256), 0, stream>>>(scores);
      gemm_bt<2, 1, MODE_AVC><<<dim3(1, 8, 32), dim3(128), 0, stream>>>(
          scores, v_t + (size_t)ch * 65536, nullptr, o16, nullptr, nullptr,
          1024, 1024, 1024, 0, 1048576, 65536, 0, ch, 1.0f, 0);
    }
    // o-projection -> fp32 lin
    gemm_bt<2, 2, MODE_F32><<<dim3(2, 256, 1), dim3(256), 0, stream>>>(
        o16, wo16 + (size_t)l * 65536, bo + l * 256, lin, nullptr, nullptr,
        256, 256, 256, 256, 0, 0, 0, 0, 1.0f, 0);
    // LN1(h + o)
    ln_k<<<dim3(8192), dim3(256), 0, stream>>>(h32, lin, g1 + l * 256,
                                               b1 + l * 256, h32, h16);
    // FF1 + relu
    gemm_bt<2, 2, MODE_BF16><<<dim3(8, 256, 1), dim3(256), 0, stream>>>(
        h16, w116 + (size_t)l * 262144, c1 + l * 1024, ff1, nullptr, nullptr,
        256, 256, 256, 1024, 0, 0, 0, 0, 1.0f, 1);
    // FF2 -> fp32 lin
    gemm_bt<2, 2, MODE_F32><<<dim3(2, 256, 1), dim3(256), 0, stream>>>(
        ff1, w216 + (size_t)l * 262144, c2 + l * 256, lin, nullptr, nullptr,
        1024, 1024, 1024, 256, 0, 0, 0, 0, 1.0f, 0);
    // LN2(x + ff); final layer writes fp32 straight to d_out
    float* y32 = (l == 1) ? (float*)d_out : h32;
    u16* y16 = (l == 1) ? nullptr : h16;
    ln_k<<<dim3(8192), dim3(256), 0, stream>>>(h32, lin, g2 + l * 256,
                                               b2 + l * 256, y32, y16);
  }
}

// Round 3
// 2036.082 us; speedup vs baseline: 1.3205x; 1.3205x over previous
//
#include <hip/hip_runtime.h>
#include <stdint.h>

using short8  = __attribute__((ext_vector_type(8))) short;
using floatx4 = __attribute__((ext_vector_type(4))) float;

typedef unsigned short u16;
typedef unsigned int u32;
typedef unsigned long long u64;

#define AS1(p) ((const __attribute__((address_space(1))) void*)(p))
#define AS3(p) ((__attribute__((address_space(3))) void*)(p))

__device__ __forceinline__ float bs2f(u16 u) { return __uint_as_float(((u32)u) << 16); }
__device__ __forceinline__ u16 f2bs(float f) {
  u32 x = __float_as_uint(f);
  x += 0x7FFFu + ((x >> 16) & 1u);   // RNE
  return (u16)(x >> 16);
}
__device__ __forceinline__ float lo16(u32 u) { return __uint_as_float(u << 16); }
__device__ __forceinline__ float hi16(u32 u) { return __uint_as_float(u & 0xFFFF0000u); }

// ---------------------------------------------------------------------------
// fp32 -> bf16 weight conversion (RNE)
// ---------------------------------------------------------------------------
__global__ __launch_bounds__(256) void cvt_k(const float* __restrict__ src,
                                             u16* __restrict__ dst, int n) {
  int i = blockIdx.x * 256 + threadIdx.x;
  if (i < n) dst[i] = f2bs(src[i]);
}

// ---------------------------------------------------------------------------
// LIF reservoir: 32 blocks (1/batch) x 1024 threads. Threads 0..511 own
// neuron r (exact fp32 state); threads 512..1023 are gather-helpers for the
// same neuron: each side sums half the change-mask words, helper partial is
// passed through LDS. rec[r] = z @ Wres[:,r] maintained incrementally.
// ---------------------------------------------------------------------------
__device__ __forceinline__ float gather4(const float* __restrict__ Wcol, u64 m, int base) {
  float s0 = 0.f, s1 = 0.f, s2 = 0.f, s3 = 0.f;
  while (m) {
    int i0 = __builtin_ctzll(m); m &= m - 1;
    s0 += Wcol[(size_t)(base + i0) << 9];
    if (m) { int i1 = __builtin_ctzll(m); m &= m - 1; s1 += Wcol[(size_t)(base + i1) << 9]; }
    if (m) { int i2 = __builtin_ctzll(m); m &= m - 1; s2 += Wcol[(size_t)(base + i2) << 9]; }
    if (m) { int i3 = __builtin_ctzll(m); m &= m - 1; s3 += Wcol[(size_t)(base + i3) << 9]; }
  }
  return (s0 + s1) + (s2 + s3);
}

__global__ __launch_bounds__(1024) void reservoir_k(
    const float* __restrict__ x,    // [32,1024,8] fp32
    const float* __restrict__ Win,  // [8,512]
    const float* __restrict__ Wres, // [512,512]
    u16* __restrict__ zout)         // [32,1024,512] bf16 (0.0/1.0, exact)
{
  const int b = blockIdx.x;
  const int tid = threadIdx.x;
  const bool owner = tid < 512;
  const int r = tid & 511;
  const int wave = tid >> 6, lane = tid & 63;
  __shared__ u64 s_on[2][8];
  __shared__ u64 s_off[2][8];
  __shared__ float hpart[512];
  __shared__ float s_x[8192];          // whole batch input, 32 KB
  const float* xb = x + (size_t)b * 8192;
  for (int i = tid; i < 8192; i += 1024) s_x[i] = xb[i];
  float win[8];
  if (owner) {
#pragma unroll
    for (int i = 0; i < 8; ++i) win[i] = Win[i * 512 + r];
  }
  const float* Wcol = Wres + r;
  u16* zb = zout + (size_t)b * 524288 + r;
  float v = 0.f, ic = 0.f, rec = 0.f;
  int zprev = 0;
  __syncthreads();
  for (int t = 0; t < 1024; ++t) {
    if (owner) {
      const float4 xa = *(const float4*)(s_x + t * 8);
      const float4 xc = *(const float4*)(s_x + t * 8 + 4);
      // v_dec = v + 0.004*(-v + i)
      const float vdec = __fadd_rn(v, __fmul_rn(0.004f, __fadd_rn(-v, ic)));
      const float xm = __fadd_rn(vdec, -0.1f);
      const int zc = (xm > 0.f) ? 1 : 0;
      v = zc ? 0.f : vdec;
      const u64 bon = __ballot(zc && !zprev);
      const u64 boff = __ballot(!zc && zprev);
      if (lane == 0) { s_on[t & 1][wave] = bon; s_off[t & 1][wave] = boff; }
      float cur = 0.f;
      cur = fmaf(win[0], xa.x, cur);
      cur = fmaf(win[1], xa.y, cur);
      cur = fmaf(win[2], xa.z, cur);
      cur = fmaf(win[3], xa.w, cur);
      cur = fmaf(win[4], xc.x, cur);
      cur = fmaf(win[5], xc.y, cur);
      cur = fmaf(win[6], xc.z, cur);
      cur = fmaf(win[7], xc.w, cur);
      // i_new = i*0.8 + (cur + rec),  rec corresponds to z_{t-1}
      ic = __fadd_rn(__fmul_rn(ic, 0.8f), __fadd_rn(cur, rec));
      zb[(size_t)t * 512] = zc ? (u16)0x3F80 : (u16)0;
      zprev = zc;
    }
    __syncthreads();                       // masks visible
    const int wbase = owner ? 0 : 4;
    float delta = 0.f;
#pragma unroll 1
    for (int w = 0; w < 4; ++w) {
      const u64 mon = s_on[t & 1][wbase + w];
      const u64 moff = s_off[t & 1][wbase + w];
      if (mon)  delta += gather4(Wcol, mon,  (wbase + w) << 6);
      if (moff) delta -= gather4(Wcol, moff, (wbase + w) << 6);
    }
    if (!owner) hpart[r] = delta;
    __syncthreads();                       // helper partial ready
    if (owner) rec += delta + hpart[r];
  }
}

// ---------------------------------------------------------------------------
// Generic bf16 MFMA GEMM: C = epilogue(A @ B^T * scale + bias)
// A [M,K] row-major (lda), B [N,K] row-major (ldb), both bf16. fp32 bias.
// BK=32, tile BM=WM*64, BN=WN*64, 4x4 16x16x32 frags/wave.
// m97-style: async global->LDS staging (width 16), LDS stride = BK (no pad).
// ---------------------------------------------------------------------------
enum { MODE_BF16 = 0, MODE_F32 = 1, MODE_DUAL = 2, MODE_QKV = 3, MODE_AVC = 4 };

template <int WM, int WN, int MODE>
__global__ __launch_bounds__(WM * WN * 64) void gemm_bt(
    const u16* __restrict__ A, const u16* __restrict__ B,
    const float* __restrict__ bias, void* __restrict__ C0,
    void* __restrict__ C1, void* __restrict__ C2, int K, int lda, int ldb,
    int ldc, long long sA, long long sB, long long sC, int pair0, float scale,
    int relu)
{
  constexpr int BM = WM * 64, BN = WN * 64, BK = 32;
  constexpr int NT = WM * WN * 64;
  constexpr int CA = BM * 4 / NT, CB = BN * 4 / NT;  // 16B chunks per thread
  __shared__ __align__(16) u16 As[BM * BK];
  __shared__ __align__(16) u16 Bs[BN * BK];
  const int tid = threadIdx.x;
  const int bz = blockIdx.z;
  const u16* Ab = A + (size_t)bz * sA + (size_t)blockIdx.y * BM * lda;
  const u16* Bb = B + (size_t)bz * sB + (size_t)blockIdx.x * BN * ldb;
  const int wavei = tid >> 6, lane = tid & 63;
  const int r16 = lane & 15, quad = lane >> 4;
  const int wm = (wavei % WM) * 64, wn = (wavei / WM) * 64;
  floatx4 acc[4][4] = {};
  for (int k0 = 0; k0 < K; k0 += BK) {
#pragma unroll
    for (int c = 0; c < CA; ++c) {
      const int idx = c * NT + tid;
      const int row = idx >> 2, kc = (idx & 3) << 3;
      __builtin_amdgcn_global_load_lds(AS1(Ab + (size_t)row * lda + k0 + kc),
                                       AS3(As + idx * 8), 16, 0, 0);
    }
#pragma unroll
    for (int c = 0; c < CB; ++c) {
      const int idx = c * NT + tid;
      const int row = idx >> 2, kc = (idx & 3) << 3;
      __builtin_amdgcn_global_load_lds(AS1(Bb + (size_t)row * ldb + k0 + kc),
                                       AS3(Bs + idx * 8), 16, 0, 0);
    }
    __syncthreads();
    short8 af[4], bfr[4];
#pragma unroll
    for (int i = 0; i < 4; ++i)
      af[i] = *(const short8*)&As[(wm + i * 16 + r16) * BK + quad * 8];
#pragma unroll
    for (int i = 0; i < 4; ++i)
      bfr[i] = *(const short8*)&Bs[(wn + i * 16 + r16) * BK + quad * 8];
#pragma unroll
    for (int i = 0; i < 4; ++i)
#pragma unroll
      for (int j = 0; j < 4; ++j)
        acc[i][j] = __builtin_amdgcn_mfma_f32_16x16x32_bf16(af[i], bfr[j], acc[i][j], 0, 0, 0);
    __syncthreads();
  }
#pragma unroll
  for (int i = 0; i < 4; ++i) {
#pragma unroll
    for (int j = 0; j < 4; ++j) {
#pragma unroll
      for (int q = 0; q < 4; ++q) {
        const int m = blockIdx.y * BM + wm + i * 16 + quad * 4 + q;
        const int n = blockIdx.x * BN + wn + j * 16 + r16;
        float val = acc[i][j][q] * scale;
        if (bias) val += bias[n];
        if (relu) val = fmaxf(val, 0.f);
        if constexpr (MODE == MODE_BF16) {
          ((u16*)C0)[(size_t)bz * sC + (size_t)m * ldc + n] = f2bs(val);
        } else if constexpr (MODE == MODE_F32) {
          ((float*)C0)[(size_t)m * ldc + n] = val;
        } else if constexpr (MODE == MODE_DUAL) {
          ((float*)C0)[(size_t)m * ldc + n] = val;
          ((u16*)C1)[(size_t)m * ldc + n] = f2bs(val);
        } else if constexpr (MODE == MODE_QKV) {
          const int b = m >> 10, s = m & 1023;
          const u16 outv = f2bs(val);
          const int h = (n & 255) >> 6, d = n & 63;
          if (n < 256)
            ((u16*)C0)[(((size_t)(b * 4 + h)) * 1024 + s) * 64 + d] = outv;  // q [B,H,S,dh]
          else if (n < 512)
            ((u16*)C1)[(((size_t)(b * 4 + h)) * 1024 + s) * 64 + d] = outv;  // k [B,H,S,dh]
          else
            ((u16*)C2)[(((size_t)(b * 4 + h)) * 64 + d) * 1024 + s] = outv;  // v^T [B,H,dh,S]
        } else if constexpr (MODE == MODE_AVC) {
          const int p = pair0 + bz;
          const size_t coff = (size_t)(p >> 2) * 262144 + (size_t)(p & 3) * 64;
          ((u16*)C0)[coff + (size_t)m * 256 + n] = f2bs(val);  // merged [B*S, H*dh]
        }
      }
    }
  }
}

// ---------------------------------------------------------------------------
// Row softmax over 1024 bf16, in place. One wave per row (16 elems/lane).
// ---------------------------------------------------------------------------
__global__ __launch_bounds__(256) void softmax_k(u16* __restrict__ s) {
  const int row = blockIdx.x * 4 + (threadIdx.x >> 6);
  const int lane = threadIdx.x & 63;
  u16* p = s + (size_t)row * 1024 + lane * 16;
  const uint4 u0 = *(const uint4*)p;
  const uint4 u1 = *(const uint4*)(p + 8);
  float f[16] = {lo16(u0.x), hi16(u0.x), lo16(u0.y), hi16(u0.y),
                 lo16(u0.z), hi16(u0.z), lo16(u0.w), hi16(u0.w),
                 lo16(u1.x), hi16(u1.x), lo16(u1.y), hi16(u1.y),
                 lo16(u1.z), hi16(u1.z), lo16(u1.w), hi16(u1.w)};
  float mx = f[0];
#pragma unroll
  for (int i = 1; i < 16; ++i) mx = fmaxf(mx, f[i]);
#pragma unroll
  for (int off = 32; off > 0; off >>= 1) mx = fmaxf(mx, __shfl_xor(mx, off));
  float sum = 0.f;
#pragma unroll
  for (int i = 0; i < 16; ++i) { f[i] = __expf(f[i] - mx); sum += f[i]; }
#pragma unroll
  for (int off = 32; off > 0; off >>= 1) sum += __shfl_xor(sum, off);
  const float inv = 1.f / sum;
  u32 o[8];
#pragma unroll
  for (int i = 0; i < 8; ++i)
    o[i] = (u32)f2bs(f[2 * i] * inv) | ((u32)f2bs(f[2 * i + 1] * inv) << 16);
  *(uint4*)p = make_uint4(o[0], o[1], o[2], o[3]);
  *(uint4*)(p + 8) = make_uint4(o[4], o[5], o[6], o[7]);
}

// ---------------------------------------------------------------------------
// Fused residual-add + LayerNorm over 256 fp32; writes fp32 and/or bf16.
// One wave per row (4 elems/lane).
// ---------------------------------------------------------------------------
__global__ __launch_bounds__(256) void ln_k(const float* __restrict__ x,
                                            const float* __restrict__ add,
                                            const float* __restrict__ g,
                                            const float* __restrict__ bta,
                                            float* __restrict__ y32,
                                            u16* __restrict__ y16) {
  const int row = blockIdx.x * 4 + (threadIdx.x >> 6);
  const int lane = threadIdx.x & 63;
  const size_t base = (size_t)row * 256 + lane * 4;
  const float4 xv = *(const float4*)(x + base);
  const float4 av = *(const float4*)(add + base);
  float sv[4] = {xv.x + av.x, xv.y + av.y, xv.z + av.z, xv.w + av.w};
  float sum = sv[0] + sv[1] + sv[2] + sv[3];
#pragma unroll
  for (int off = 32; off > 0; off >>= 1) sum += __shfl_xor(sum, off);
  const float mean = sum * (1.f / 256.f);
  float var = 0.f;
  float d[4];
#pragma unroll
  for (int i = 0; i < 4; ++i) { d[i] = sv[i] - mean; var += d[i] * d[i]; }
#pragma unroll
  for (int off = 32; off > 0; off >>= 1) var += __shfl_xor(var, off);
  var *= (1.f / 256.f);
  const float inv = 1.f / sqrtf(var + 1e-5f);
  float yv[4];
#pragma unroll
  for (int i = 0; i < 4; ++i)
    yv[i] = d[i] * inv * g[lane * 4 + i] + bta[lane * 4 + i];
  if (y32) *(float4*)(y32 + base) = make_float4(yv[0], yv[1], yv[2], yv[3]);
  if (y16) {
    const u32 p0 = (u32)f2bs(yv[0]) | ((u32)f2bs(yv[1]) << 16);
    const u32 p1 = (u32)f2bs(yv[2]) | ((u32)f2bs(yv[3]) << 16);
    *(uint2*)(y16 + base) = make_uint2(p0, p1);
  }
}

// ---------------------------------------------------------------------------
extern "C" void kernel_launch(void* const* d_in, const int* in_sizes, int n_in,
                              void* d_out, int out_size, void* d_ws,
                              size_t ws_size, hipStream_t stream) {
  (void)in_sizes; (void)n_in; (void)out_size; (void)ws_size;
  const float* x     = (const float*)d_in[0];   // [32,1024,8]
  const float* Win   = (const float*)d_in[1];   // [8,512]
  const float* Wres  = (const float*)d_in[2];   // [512,512]
  const float* Wread = (const float*)d_in[3];   // [256,512]
  const float* bread = (const float*)d_in[4];   // [256]
  const float* Wqkv  = (const float*)d_in[5];   // [2,768,256]
  const float* bqkv  = (const float*)d_in[6];   // [2,768]
  const float* Wo    = (const float*)d_in[7];   // [2,256,256]
  const float* bo    = (const float*)d_in[8];   // [2,256]
  const float* g1    = (const float*)d_in[9];
  const float* b1    = (const float*)d_in[10];
  const float* g2    = (const float*)d_in[11];
  const float* b2    = (const float*)d_in[12];
  const float* W1    = (const float*)d_in[13];  // [2,1024,256]
  const float* c1    = (const float*)d_in[14];  // [2,1024]
  const float* W2    = (const float*)d_in[15];  // [2,256,1024]
  const float* c2    = (const float*)d_in[16];  // [2,256]

  char* ws = (char*)d_ws;
  size_t off = 0;
  auto carve = [&](size_t bytes) {
    char* p = ws + off;
    off += (bytes + 255) & ~(size_t)255;
    return p;
  };
  u16* z      = (u16*)carve((size_t)32 * 1024 * 512 * 2);    // 33.6 MB spikes (bf16)
  u16* wrd16  = (u16*)carve((size_t)256 * 512 * 2);          // bf16 weights:
  u16* wqkv16 = (u16*)carve((size_t)2 * 768 * 256 * 2);
  u16* wo16   = (u16*)carve((size_t)2 * 256 * 256 * 2);
  u16* w116   = (u16*)carve((size_t)2 * 1024 * 256 * 2);
  u16* w216   = (u16*)carve((size_t)2 * 256 * 1024 * 2);
  u16* q_s    = (u16*)carve((size_t)128 * 1024 * 64 * 2);    // [B*H,S,dh]
  u16* k_s    = (u16*)carve((size_t)128 * 1024 * 64 * 2);
  u16* v_t    = (u16*)carve((size_t)128 * 64 * 1024 * 2);    // [B*H,dh,S]
  float* h32  = (float*)carve((size_t)32768 * 256 * 4);      // residual fp32
  float* lin  = (float*)carve((size_t)32768 * 256 * 4);      // o-proj/ff2 fp32
  u16* h16    = (u16*)carve((size_t)32768 * 256 * 2);        // bf16 GEMM input
  u16* ff1    = (u16*)carve((size_t)32768 * 1024 * 2);       // ff1 out (aliases scores)
  u16* o16    = h16;   // attention-out reuses h16 (qkv already consumed it)
  u16* scores = ff1;   // 32-pair score chunk == ff1 size (64 MB)

  // weight conversions (fp32 -> bf16)
  cvt_k<<<dim3(512), dim3(256), 0, stream>>>(Wread, wrd16, 131072);
  cvt_k<<<dim3(1536), dim3(256), 0, stream>>>(Wqkv, wqkv16, 393216);
  cvt_k<<<dim3(512), dim3(256), 0, stream>>>(Wo, wo16, 131072);
  cvt_k<<<dim3(2048), dim3(256), 0, stream>>>(W1, w116, 524288);
  cvt_k<<<dim3(2048), dim3(256), 0, stream>>>(W2, w216, 524288);

  reservoir_k<<<dim3(32), dim3(1024), 0, stream>>>(x, Win, Wres, z);

  // readout: h = z @ Wread^T + bread  (dual fp32 + bf16)
  gemm_bt<2, 2, MODE_DUAL><<<dim3(2, 256, 1), dim3(256), 0, stream>>>(
      z, wrd16, bread, h32, h16, nullptr, 512, 512, 512, 256, 0, 0, 0, 0, 1.0f, 0);

  for (int l = 0; l < 2; ++l) {
    // qkv + scatter into q_s / k_s / v_t
    gemm_bt<2, 2, MODE_QKV><<<dim3(6, 256, 1), dim3(256), 0, stream>>>(
        h16, wqkv16 + (size_t)l * 196608, bqkv + l * 768, q_s, k_s, v_t, 256,
        256, 256, 0, 0, 0, 0, 0, 1.0f, 0);
    // attention in chunks of 32 (b,h)-pairs
    for (int ch = 0; ch < 128; ch += 32) {
      gemm_bt<2, 2, MODE_BF16><<<dim3(8, 8, 32), dim3(256), 0, stream>>>(
          q_s + (size_t)ch * 65536, k_s + (size_t)ch * 65536, nullptr, scores,
          nullptr, nullptr, 64, 64, 64, 1024, 65536, 65536, 1048576, 0,
          0.125f, 0);
      softmax_k<<<dim3(8192), dim3(256), 0, stream>>>(scores);
      gemm_bt<2, 1, MODE_AVC><<<dim3(1, 8, 32), dim3(128), 0, stream>>>(
          scores, v_t + (size_t)ch * 65536, nullptr, o16, nullptr, nullptr,
          1024, 1024, 1024, 0, 1048576, 65536, 0, ch, 1.0f, 0);
    }
    // o-projection -> fp32 lin
    gemm_bt<2, 2, MODE_F32><<<dim3(2, 256, 1), dim3(256), 0, stream>>>(
        o16, wo16 + (size_t)l * 65536, bo + l * 256, lin, nullptr, nullptr,
        256, 256, 256, 256, 0, 0, 0, 0, 1.0f, 0);
    // LN1(h + o)
    ln_k<<<dim3(8192), dim3(256), 0, stream>>>(h32, lin, g1 + l * 256,
                                               b1 + l * 256, h32, h16);
    // FF1 + relu
    gemm_bt<2, 2, MODE_BF16><<<dim3(8, 256, 1), dim3(256), 0, stream>>>(
        h16, w116 + (size_t)l * 262144, c1 + l * 1024, ff1, nullptr, nullptr,
        256, 256, 256, 1024, 0, 0, 0, 0, 1.0f, 1);
    // FF2 -> fp32 lin
    gemm_bt<2, 2, MODE_F32><<<dim3(2, 256, 1), dim3(256), 0, stream>>>(
        ff1, w216 + (size_t)l * 262144, c2 + l * 256, lin, nullptr, nullptr,
        1024, 1024, 1024, 256, 0, 0, 0, 0, 1.0f, 0);
    // LN2(x + ff); final layer writes fp32 straight to d_out
    float* y32 = (l == 1) ? (float*)d_out : h32;
    u16* y16 = (l == 1) ? nullptr : h16;
    ln_k<<<dim3(8192), dim3(256), 0, stream>>>(h32, lin, g2 + l * 256,
                                               b2 + l * 256, y32, y16);
  }
}